// Round 1
// 213.483 us; speedup vs baseline: 1.0210x; 1.0210x over previous
//
#include <hip/hip_runtime.h>
#include <cstdio>
#include <cstdint>

// ---------------------------------------------------------------------------
// Transformer-XL relative MHA, MI355X/gfx950.  B=16 T=512 D=512 H=8 hd=64.
// Round 12: proj_all moved from direct-global fragment loads (depth-1 reg
// prefetch, ~400 TF effective, latency/L2-bound: MfmaUtil 15%) to the m97
// verified structure: 128x128 block tile, BK=64, 4 waves, global_load_lds
// width-16 staging into 32KB LDS, ds_read_b128 fragments, 2 barriers/K-step.
// pk() packed layout means staging is linear (1KB contiguous per 16x32 chunk)
// and fragment extraction is byte-identical to the old code -> same results.
// XCD-aware bijective block swizzle added (1280 % 8 == 0).
// megaprep / flash_attn / out_gemm unchanged from R11.
// pack(r,k) = (r>>4)*8192 + (k>>5)*512 + ((k>>3)&3)*128 + (r&15)*8 + (k&7)
// ---------------------------------------------------------------------------

typedef short s16x8 __attribute__((ext_vector_type(8)));
typedef float f32x4 __attribute__((ext_vector_type(4)));
typedef unsigned short u16x4 __attribute__((ext_vector_type(4)));
typedef unsigned short u16x8 __attribute__((ext_vector_type(8)));

#define CSCALE 0.1803368801111204f  // log2(e)/8

#if __has_builtin(__builtin_amdgcn_exp2f)
#define EXP2(x) __builtin_amdgcn_exp2f(x)
#else
#define EXP2(x) exp2f(x)
#endif

__device__ __forceinline__ unsigned short f2bf(float f) {  // RNE
  unsigned int u = __builtin_bit_cast(unsigned int, f);
  unsigned int r = (u + 0x7FFFu + ((u >> 16) & 1u)) >> 16;
  return (unsigned short)r;
}
__device__ __forceinline__ float bf2f(unsigned short h) {
  unsigned int u = ((unsigned int)h) << 16;
  return __builtin_bit_cast(float, u);
}
// fragment-strip packing: strips of 16 rows x 512 k (8192 shorts)
__device__ __forceinline__ size_t pk(int row, int col) {
  return (size_t)(row >> 4) * 8192 + (col >> 5) * 512 + ((col >> 3) & 3) * 128 +
         (row & 15) * 8 + (col & 7);
}

// async global->LDS, 16B per lane. Global src is PER-LANE; LDS dst is the
// wave-uniform base (HW adds lane*16).
__device__ __forceinline__ void gload_lds16(const unsigned short* g,
                                            unsigned short* l) {
  __builtin_amdgcn_global_load_lds(
      (const __attribute__((address_space(1))) unsigned int*)g,
      (__attribute__((address_space(3))) unsigned int*)l, 16, 0, 0);
}

// ---------------- fused prep (vectorized stores) ---------------------------
__global__ __launch_bounds__(256) void megaprep(
    const float* __restrict__ x, const float* __restrict__ g,
    const float* __restrict__ bb, unsigned short* __restrict__ xpk,
    const float* __restrict__ pe, unsigned short* __restrict__ pepk,
    const float* __restrict__ Wq, const float* __restrict__ Wk,
    const float* __restrict__ Wp, const float* __restrict__ Wv,
    const float* __restrict__ Wo, const float* __restrict__ bq,
    const float* __restrict__ bk, unsigned short* __restrict__ wqk,
    unsigned short* __restrict__ wpm, unsigned short* __restrict__ wvm,
    unsigned short* __restrict__ wom, float* __restrict__ bqk) {
  const int bid = blockIdx.x, tid = threadIdx.x;
  if (bid < 2048) {  // LN: row = bid*4 + wave
    const int wave = tid >> 6, lane = tid & 63;
    const int row = bid * 4 + wave;
    const int c0 = lane * 8;
    const float* xr = x + (size_t)row * 512 + c0;
    float4 v0 = *(const float4*)xr;
    float4 v1 = *(const float4*)(xr + 4);
    float vv[8] = {v0.x, v0.y, v0.z, v0.w, v1.x, v1.y, v1.z, v1.w};
    float s = 0.f, ss = 0.f;
#pragma unroll
    for (int j = 0; j < 8; ++j) { s += vv[j]; ss += vv[j] * vv[j]; }
#pragma unroll
    for (int d = 1; d < 64; d <<= 1) {
      s += __shfl_xor(s, d, 64);
      ss += __shfl_xor(ss, d, 64);
    }
    const float mu = s * (1.0f / 512.0f);
    const float var = ss * (1.0f / 512.0f) - mu * mu;
    const float rstd = rsqrtf(var + 1e-5f);
    u16x8 o;
#pragma unroll
    for (int j = 0; j < 8; ++j)
      o[j] = f2bf((vv[j] - mu) * rstd * g[c0 + j] + bb[c0 + j]);
    *(u16x8*)(xpk + pk(row, c0)) = o;
  } else if (bid < 6144) {  // pe: 8 elems/thread
    int gid = (bid - 2048) * 256 + tid;
    int e = gid * 8;  // over 16384*512
    int r = e >> 9, c = e & 511;
    int b = r >> 10, u = r & 1023;
    u16x8 o = {0, 0, 0, 0, 0, 0, 0, 0};
    if (u < 1023) {
      const float* src = pe + (size_t)(b * 1023 + u) * 512 + c;
      float4 v0 = *(const float4*)src;
      float4 v1 = *(const float4*)(src + 4);
      o[0] = f2bf(v0.x); o[1] = f2bf(v0.y); o[2] = f2bf(v0.z); o[3] = f2bf(v0.w);
      o[4] = f2bf(v1.x); o[5] = f2bf(v1.y); o[6] = f2bf(v1.z); o[7] = f2bf(v1.w);
    }
    *(u16x8*)(pepk + (size_t)b * 524288 + pk(u, c)) = o;
  } else {  // weights: 8 elems/thread
    int gid = (bid - 6144) * 256 + tid;
    int idx = gid * 8;  // over 5*262144
    int region = idx >> 18, off = idx & 262143;
    const float* src = (region == 0)   ? Wq
                       : (region == 1) ? Wk
                       : (region == 2) ? Wp
                       : (region == 3) ? Wv
                                       : Wo;
    float4 v0 = *(const float4*)(src + off);
    float4 v1 = *(const float4*)(src + off + 4);
    u16x8 o;
    o[0] = f2bf(v0.x); o[1] = f2bf(v0.y); o[2] = f2bf(v0.z); o[3] = f2bf(v0.w);
    o[4] = f2bf(v1.x); o[5] = f2bf(v1.y); o[6] = f2bf(v1.z); o[7] = f2bf(v1.w);
    int n = off >> 9, k = off & 511;
    unsigned short* dst;
    int nrow = n;
    if (region == 0) { dst = wqk; }
    else if (region == 1) { dst = wqk; nrow = n + 512; }
    else if (region == 2) { dst = wpm; }
    else if (region == 3) { dst = wvm; }
    else { dst = wom; }
    *(u16x8*)(dst + pk(nrow, k)) = o;
    if (idx < 1024) {
#pragma unroll
      for (int j = 0; j < 8; j++) {
        int ii = idx + j;
        bqk[ii] = (ii < 512) ? bq[ii] : bk[ii - 512];
      }
    }
  }
}

// ---------------- 128x128 LDS-staged GEMM core (m97 structure) -------------
// 4 waves, each owns a 64x64 quadrant (wr=wave>>1, wc=wave&1). K=512 in 8
// steps of BK=64. Per step: each wave stages 2 A-strips + 2 B-strips (2KB
// each, linear in the pk() layout) via global_load_lds, barrier, 16
// ds_read_b128 + 32 MFMA, barrier. Fragment byte offsets are identical to
// the old direct-load path, so accumulation is bit-identical.
__device__ __forceinline__ void gemm128_lds(
    const unsigned short* __restrict__ Apk, const unsigned short* __restrict__ Bpk,
    int mstrip0, int nstrip0, unsigned short* __restrict__ lA,
    unsigned short* __restrict__ lB, int wave, int lane, f32x4 acc[4][4]) {
  const int wr = wave >> 1, wc = wave & 1;
  // staging sources: this wave covers strips (2*wave, 2*wave+1)
  const unsigned short* ga = Apk + (size_t)(mstrip0 + 2 * wave) * 8192 + lane * 8;
  const unsigned short* gb = Bpk + (size_t)(nstrip0 + 2 * wave) * 8192 + lane * 8;
  unsigned short* la_w = lA + (2 * wave) * 1024;
  unsigned short* lb_w = lB + (2 * wave) * 1024;
  // fragment read bases for this wave's quadrant
  const unsigned short* lard = lA + (wr * 4) * 1024 + lane * 8;
  const unsigned short* lbrd = lB + (wc * 4) * 1024 + lane * 8;

  for (int ks = 0; ks < 8; ++ks) {
#pragma unroll
    for (int s = 0; s < 2; ++s) {
#pragma unroll
      for (int hf = 0; hf < 2; ++hf) {
        gload_lds16(ga + (size_t)s * 8192 + ks * 1024 + hf * 512,
                    la_w + s * 1024 + hf * 512);
        gload_lds16(gb + (size_t)s * 8192 + ks * 1024 + hf * 512,
                    lb_w + s * 1024 + hf * 512);
      }
    }
    __syncthreads();  // drains vmcnt -> staged tile visible
#pragma unroll
    for (int kk = 0; kk < 2; ++kk) {
      s16x8 af[4], bf[4];
#pragma unroll
      for (int mt = 0; mt < 4; ++mt)
        af[mt] = *(const s16x8*)(lard + mt * 1024 + kk * 512);
#pragma unroll
      for (int nt = 0; nt < 4; ++nt)
        bf[nt] = *(const s16x8*)(lbrd + nt * 1024 + kk * 512);
#pragma unroll
      for (int mt = 0; mt < 4; ++mt)
#pragma unroll
        for (int nt = 0; nt < 4; ++nt)
          acc[mt][nt] = __builtin_amdgcn_mfma_f32_16x16x32_bf16(
              af[mt], bf[nt], acc[mt][nt], 0, 0, 0);
    }
    __syncthreads();  // tile consumed -> safe to overwrite next step
  }
}

// ---------------- direct-load 64x64 GEMM core (kept for out_gemm) ----------
__device__ __forceinline__ void gemm64_direct(
    const unsigned short* __restrict__ Apk, const unsigned short* __restrict__ Bpk,
    int mstrip0, int nstrip0, int lane, f32x4 acc[4][4]) {
  const unsigned short* ab = Apk + (size_t)mstrip0 * 8192 + lane * 8;
  const unsigned short* bb = Bpk + (size_t)nstrip0 * 8192 + lane * 8;
  s16x8 af[2][4], bf[2][4];
#pragma unroll
  for (int mt = 0; mt < 4; ++mt) af[0][mt] = *(const s16x8*)(ab + mt * 8192);
#pragma unroll
  for (int nt = 0; nt < 4; ++nt) bf[0][nt] = *(const s16x8*)(bb + nt * 8192);
#pragma unroll
  for (int kc = 0; kc < 16; ++kc) {
    const int cur = kc & 1, nxt = cur ^ 1;
    if (kc < 15) {
#pragma unroll
      for (int mt = 0; mt < 4; ++mt)
        af[nxt][mt] = *(const s16x8*)(ab + (size_t)mt * 8192 + (kc + 1) * 512);
#pragma unroll
      for (int nt = 0; nt < 4; ++nt)
        bf[nxt][nt] = *(const s16x8*)(bb + (size_t)nt * 8192 + (kc + 1) * 512);
    }
#pragma unroll
    for (int mt = 0; mt < 4; ++mt)
#pragma unroll
      for (int nt = 0; nt < 4; ++nt)
        acc[mt][nt] = __builtin_amdgcn_mfma_f32_16x16x32_bf16(
            af[cur][mt], bf[cur][nt], acc[mt][nt], 0, 0, 0);
  }
}

// merged projections: 128x128 block tiles.
// qk: blocks [0,512)   = 64 m x 8 n   (A=xpk 8192 rows, B=wqk 1024 cols)
// p : blocks [512,1024)= 16 b x 8 m x 4 n (A=pepk per-b 1024 rows, B=wpm 512)
// v : blocks [1024,1280)= 64 m x 4 n  (A=xpk, B=wvm 512 cols)
__global__ __launch_bounds__(256) void proj_all(
    const unsigned short* __restrict__ xpk, const unsigned short* __restrict__ pepk,
    const unsigned short* __restrict__ wqk, const unsigned short* __restrict__ wpm,
    const unsigned short* __restrict__ wvm, const float* __restrict__ bqk,
    const float* __restrict__ bp, const float* __restrict__ bv,
    const float* __restrict__ cbv, const float* __restrict__ pbv,
    unsigned short* __restrict__ qc, unsigned short* __restrict__ qp,
    unsigned short* __restrict__ kb, unsigned short* __restrict__ pbuf,
    unsigned short* __restrict__ vth) {
  __shared__ __align__(16) unsigned short lA[8192];  // 16KB: 128 rows x 64 k
  __shared__ __align__(16) unsigned short lB[8192];  // 16KB: 128 cols x 64 k
  const int tid = threadIdx.x, lane = tid & 63, wave = tid >> 6;
  int bid = blockIdx.x;
  bid = (bid & 7) * 160 + (bid >> 3);  // XCD swizzle (1280 % 8 == 0)
  const int wr = wave >> 1, wc = wave & 1;
  const int fr = lane & 15, hi2 = lane >> 4;
  f32x4 fz = {0.f, 0.f, 0.f, 0.f};
  f32x4 acc[4][4];
#pragma unroll
  for (int i = 0; i < 4; i++)
#pragma unroll
    for (int j = 0; j < 4; j++) acc[i][j] = fz;

  if (bid < 512) {  // qk
    int m_t = bid >> 3, n_t = bid & 7;
    gemm128_lds(xpk, wqk, m_t * 8, n_t * 8, lA, lB, wave, lane, acc);
    int m0 = m_t * 128 + wr * 64, n0 = n_t * 128 + wc * 64;
#pragma unroll
    for (int nt = 0; nt < 4; ++nt) {
      int col = n0 + nt * 16 + fr;
      float bval = bqk[col];
#pragma unroll
      for (int mt = 0; mt < 4; ++mt) {
        int row = m0 + mt * 16 + hi2 * 4;
        int b = row >> 9, s15 = row & 15, s16i = (row & 511) >> 4;
        if (col < 512) {
          int h = col >> 6, cc = col & 63;
          size_t idx = ((size_t)(b * 8 + h) * 32 + s16i) * 1024 +
                       (cc >> 5) * 512 + ((cc & 31) >> 3) * 128 + (cc & 7);
          float cbc = cbv[col], pbc = pbv[col];
#pragma unroll
          for (int r = 0; r < 4; ++r) {
            float val = acc[mt][nt][r] + bval;
            qc[idx + (s15 + r) * 8] = f2bf((val + cbc) * CSCALE);
            qp[idx + (s15 + r) * 8] = f2bf((val + pbc) * CSCALE);
          }
        } else {
          int c2 = col - 512, h = c2 >> 6, cc = c2 & 63;
          size_t idx = ((size_t)(b * 8 + h) * 32 + s16i) * 1024 +
                       (cc >> 5) * 512 + ((cc & 31) >> 3) * 128 + (cc & 7);
#pragma unroll
          for (int r = 0; r < 4; ++r)
            kb[idx + (s15 + r) * 8] = f2bf(acc[mt][nt][r] + bval);
        }
      }
    }
  } else if (bid < 1024) {  // p (per-b packed A)
    int p_id = bid - 512;
    int b = p_id >> 5, rem = p_id & 31;
    int m_tb = rem >> 2, n_t = rem & 3;
    gemm128_lds(pepk + (size_t)b * 524288, wpm, m_tb * 8, n_t * 8, lA, lB,
                wave, lane, acc);
    int u0 = m_tb * 128 + wr * 64, n0 = n_t * 128 + wc * 64;
#pragma unroll
    for (int nt = 0; nt < 4; ++nt) {
      int col = n0 + nt * 16 + fr;
      float bval = bp[col];
      int h = col >> 6, cc = col & 63;
      size_t cbase = (size_t)(b * 8 + h) * 64 * 1024 + (cc >> 5) * 512 +
                     ((cc & 31) >> 3) * 128 + (cc & 7);
#pragma unroll
      for (int mt = 0; mt < 4; ++mt) {
        int ub = u0 + mt * 16 + hi2 * 4;
#pragma unroll
        for (int r = 0; r < 4; ++r) {
          int u = ub + r;
          float val = (u >= 1023) ? 0.f : (acc[mt][nt][r] + bval);
          pbuf[cbase + (size_t)(u >> 4) * 1024 + (u & 15) * 8] = f2bf(val);
        }
      }
    }
  } else {  // v -> vT packed
    int v_id = bid - 1024;
    int m_t = v_id >> 2, n_t = v_id & 3;
    gemm128_lds(xpk, wvm, m_t * 8, n_t * 8, lA, lB, wave, lane, acc);
    int m0 = m_t * 128 + wr * 64, n0 = n_t * 128 + wc * 64;
#pragma unroll
    for (int nt = 0; nt < 4; ++nt) {
      int col = n0 + nt * 16 + fr;
      float bval = bv[col];
      int h = col >> 6, d = col & 63;
#pragma unroll
      for (int mt = 0; mt < 4; ++mt) {
        int rowb = m0 + mt * 16 + hi2 * 4;
        int b = rowb >> 9, t = rowb & 511;
        size_t idx = ((size_t)((b * 8 + h) * 4 + (d >> 4)) * 16 + (t >> 5)) * 512 +
                     ((t & 31) >> 3) * 128 + (d & 15) * 8 + (t & 7);
        u16x4 hv;
#pragma unroll
        for (int r = 0; r < 4; ++r) hv[r] = f2bf(acc[mt][nt][r] + bval);
        *(u16x4*)(vth + idx) = hv;
      }
    }
  }
}

__global__ __launch_bounds__(256) void out_gemm(
    const unsigned short* __restrict__ ctxpk, const unsigned short* __restrict__ wom,
    const float* __restrict__ bo, float* __restrict__ out) {
  const int tid = threadIdx.x, lane = tid & 63, wave = tid >> 6;
  const int w = blockIdx.x * 4 + wave;  // 1024 waves: 128 m x 8 n
  const int fr = lane & 15, hi2 = lane >> 4;
  int m_t = w >> 3, n_t = w & 7;
  f32x4 fz = {0.f, 0.f, 0.f, 0.f};
  f32x4 acc[4][4];
#pragma unroll
  for (int i = 0; i < 4; i++)
#pragma unroll
    for (int j = 0; j < 4; j++) acc[i][j] = fz;
  gemm64_direct(ctxpk, wom, m_t * 4, n_t * 4, lane, acc);
  int m0 = m_t * 64, n0 = n_t * 64;
#pragma unroll
  for (int nt = 0; nt < 4; ++nt) {
    int col = n0 + nt * 16 + fr;
    float bval = bo[col];
#pragma unroll
    for (int mt = 0; mt < 4; ++mt) {
      int row = m0 + mt * 16 + hi2 * 4;
#pragma unroll
      for (int r = 0; r < 4; ++r)
        out[(size_t)(row + r) * 512 + col] = acc[mt][nt][r] + bval;
    }
  }
}

// ---------------- barrier-free flash attention, static-buffer pipeline -----
// grid 1024; id%128=(b,h). Wave owns 16 q-rows. Fixed-max softmax. Two
// statically-named fragment buffer sets; step loop unrolled 2x so every
// buffer reference is compile-time (NO dynamic array indexing -> no scratch).
__global__ __launch_bounds__(256) void flash_attn(
    const unsigned short* __restrict__ qc, const unsigned short* __restrict__ qp,
    const unsigned short* __restrict__ kb, const unsigned short* __restrict__ pm,
    const unsigned short* __restrict__ vth, unsigned short* __restrict__ ctxpk) {
  const int id = blockIdx.x;
  const int bh = id & 127, b = bh >> 3, h = bh & 7;
  const int s_blk = id >> 7;
  const int tid = threadIdx.x, wave = tid >> 6, lane = tid & 63;
  const int fr = lane & 15, hi2 = lane >> 4, fc = hi2 * 8;
  const int s0w = s_blk * 64 + wave * 16;
  const int crow = hi2 * 4;

  __shared__ __align__(16) unsigned short Ph_s[4][16][40];
  unsigned short(*Phw)[40] = Ph_s[wave];

  int srcl[4];
#pragma unroll
  for (int r = 0; r < 4; ++r) srcl[r] = (hi2 << 4) | ((fr - (crow + r) - 1) & 15);

  const size_t qtb = ((size_t)(b * 8 + h) * 32 + (s0w >> 4)) * 1024 + lane * 8;
  s16x8 aqc0 = *(const s16x8*)(qc + qtb);
  s16x8 aqc1 = *(const s16x8*)(qc + qtb + 512);
  s16x8 aqp0 = *(const s16x8*)(qp + qtb);
  s16x8 aqp1 = *(const s16x8*)(qp + qtb + 512);

  const unsigned short* kpk = kb + (size_t)(b * 8 + h) * 32 * 1024 + lane * 8;
  const unsigned short* ppk = pm + (size_t)(b * 8 + h) * 64 * 1024 + lane * 8;
  const unsigned short* vhk = vth + (size_t)(b * 8 + h) * 64 * 512 + lane * 8;

  f32x4 fz = {0.f, 0.f, 0.f, 0.f};
  f32x4 Oacc[4] = {fz, fz, fz, fz};
  float lsum[4] = {0.f, 0.f, 0.f, 0.f};

  s16x8 kfA[4], pfA[6], vfA[4], kfB[4], pfB[6], vfB[4];

  // load fragments for `step` into the given (statically-named) buffers
#define LOADF(step, kf, pf, vf)                                              \
  {                                                                          \
    const int t0_ = (step) * 32;                                             \
    const int u0w_ = t0_ - s0w + 496;                                        \
    const int kt_ = t0_ >> 4, ut_ = u0w_ >> 4, vt_ = t0_ >> 5;               \
    _Pragma("unroll") for (int nt = 0; nt < 2; ++nt) {                       \
      const unsigned short* kr = kpk + (size_t)(kt_ + nt) * 1024;            \
      kf[2 * nt] = *(const s16x8*)kr;                                        \
      kf[2 * nt + 1] = *(const s16x8*)(kr + 512);                            \
    }                                                                        \
    _Pragma("unroll") for (int nt = 0; nt < 3; ++nt) {                       \
      const unsigned short* pr = ppk + (size_t)(ut_ + nt) * 1024;            \
      pf[2 * nt] = *(const s16x8*)pr;                                        \
      pf[2 * nt + 1] = *(const s16x8*)(pr + 512);                            \
    }                                                                        \
    _Pragma("unroll") for (int nt = 0; nt < 4; ++nt)                         \
        vf[nt] = *(const s16x8*)(vhk + (size_t)(nt * 16 + vt_) * 512);       \
  }

  // one attention step using the given buffers
#define STEPF(kf, pf, vf)                                                    \
  {                                                                          \
    f32x4 sc[2] = {fz, fz};                                                  \
    _Pragma("unroll") for (int nt = 0; nt < 2; ++nt) {                       \
      sc[nt] = __builtin_amdgcn_mfma_f32_16x16x32_bf16(aqc0, kf[2 * nt],     \
                                                       sc[nt], 0, 0, 0);     \
      sc[nt] = __builtin_amdgcn_mfma_f32_16x16x32_bf16(aqc1, kf[2 * nt + 1], \
                                                       sc[nt], 0, 0, 0);     \
    }                                                                        \
    f32x4 sp[3];                                                             \
    _Pragma("unroll") for (int nt = 0; nt < 3; ++nt) {                       \
      f32x4 t = fz;                                                          \
      t = __builtin_amdgcn_mfma_f32_16x16x32_bf16(aqp0, pf[2 * nt], t, 0, 0, 0); \
      t = __builtin_amdgcn_mfma_f32_16x16x32_bf16(aqp1, pf[2 * nt + 1], t, 0, 0, 0); \
      sp[nt] = t;                                                            \
    }                                                                        \
    float sj[3][4];                                                          \
    _Pragma("unroll") for (int j = 0; j < 3; ++j)                            \
        _Pragma("unroll") for (int r = 0; r < 4; ++r)                        \
        sj[j][r] = __shfl(sp[j][r], srcl[r], 64);                            \
    _Pragma("unroll") for (int nt = 0; nt < 2; ++nt) {                       \
      int tc = nt * 16 + fr;                                                 \
      _Pragma("unroll") for (int r = 0; r < 4; ++r) {                        \
        float pos = (fr <= crow + r) ? sj[nt][r] : sj[nt + 1][r];            \
        float e = EXP2(sc[nt][r] + pos);                                     \
        lsum[r] += e;                                                        \
        Phw[crow + r][tc] = f2bf(e);                                         \
      }                                                                      \
    }                                                                        \
    s16x8 ah = *(const s16x8*)&Phw[fr][fc];                                  \
    _Pragma("unroll") for (int nt = 0; nt < 4; ++nt)                         \
        Oacc[nt] = __builtin_amdgcn_mfma_f32_16x16x32_bf16(ah, vf[nt],       \
                                                           Oacc[nt], 0, 0, 0); \
  }

  LOADF(0, kfA, pfA, vfA);
  for (int s2 = 0; s2 < 8; ++s2) {
    LOADF(2 * s2 + 1, kfB, pfB, vfB);
    STEPF(kfA, pfA, vfA);
    if (s2 < 7) LOADF(2 * s2 + 2, kfA, pfA, vfA);
    STEPF(kfB, pfB, vfB);
  }
#undef LOADF
#undef STEPF

#pragma unroll
  for (int d = 1; d < 16; d <<= 1)
#pragma unroll
    for (int r = 0; r < 4; ++r) lsum[r] += __shfl_xor(lsum[r], d, 64);
  // epilogue: ctx in packed A-fragment layout for the out GEMM
#pragma unroll
  for (int nt = 0; nt < 4; ++nt)
#pragma unroll
    for (int r = 0; r < 4; ++r) {
      float o = Oacc[nt][r] / lsum[r];
      int row = b * 512 + s0w + crow + r;
      int col = h * 64 + nt * 16 + fr;
      ctxpk[pk(row, col)] = f2bf(o);
    }
}

// ---------------------------------------------------------------------------
extern "C" void kernel_launch(void* const* d_in, const int* in_sizes, int n_in,
                              void* d_out, int out_size, void* d_ws,
                              size_t ws_size, hipStream_t stream) {
  const float* x = (const float*)d_in[0];
  const float* pe = (const float*)d_in[1];
  const float* ln_g = (const float*)d_in[2];
  const float* ln_b = (const float*)d_in[3];
  const float* Wq = (const float*)d_in[4];
  const float* bq = (const float*)d_in[5];
  const float* Wk = (const float*)d_in[6];
  const float* bk = (const float*)d_in[7];
  const float* Wv = (const float*)d_in[8];
  const float* bv = (const float*)d_in[9];
  const float* Wp = (const float*)d_in[10];
  const float* bp = (const float*)d_in[11];
  const float* cb = (const float*)d_in[12];
  const float* pb = (const float*)d_in[13];
  const float* Wo = (const float*)d_in[14];
  const float* bo = (const float*)d_in[15];
  float* out = (float*)d_out;

  char* ws = (char*)d_ws;
  size_t off = 0;
  auto alloc = [&](size_t bytes) -> char* {
    char* ptr = ws + off;
    off = (off + bytes + 255) & ~(size_t)255;
    return ptr;
  };
  // xn packed (8.4 MB) -> reused as ctx packed after proj_all completes
  unsigned short* xpk = (unsigned short*)alloc((size_t)8192 * 512 * 2);
  unsigned short* ctxpk = xpk;
  unsigned short* pepk = (unsigned short*)alloc((size_t)16384 * 512 * 2);
  unsigned short* vt_hi = (unsigned short*)alloc((size_t)8192 * 512 * 2);
  unsigned short* wqk = (unsigned short*)alloc((size_t)1024 * 512 * 2);
  unsigned short* wpm = (unsigned short*)alloc((size_t)512 * 512 * 2);
  unsigned short* wvm = (unsigned short*)alloc((size_t)512 * 512 * 2);
  unsigned short* wom = (unsigned short*)alloc((size_t)512 * 512 * 2);
  float* bqk = (float*)alloc(1024 * 4);
  unsigned short* qc = (unsigned short*)alloc((size_t)8192 * 512 * 2);
  unsigned short* qp = (unsigned short*)alloc((size_t)8192 * 512 * 2);
  unsigned short* kbuf = (unsigned short*)alloc((size_t)8192 * 512 * 2);
  unsigned short* pbuf = (unsigned short*)alloc((size_t)16384 * 512 * 2);

  if (ws_size < off) {
    fprintf(stderr, "kernel_launch: ws too small (need %zu, have %zu)\n", off,
            ws_size);
    return;
  }

  megaprep<<<6784, 256, 0, stream>>>(x, ln_g, ln_b, xpk, pe, pepk, Wq, Wk, Wp,
                                     Wv, Wo, bq, bk, wqk, wpm, wvm, wom, bqk);
  proj_all<<<1280, 256, 0, stream>>>(xpk, pepk, wqk, wpm, wvm, bqk, bp, bv,
                                     cb, pb, qc, qp, kbuf, pbuf, vt_hi);
  flash_attn<<<1024, 256, 0, stream>>>(qc, qp, kbuf, pbuf, vt_hi, ctxpk);
  out_gemm<<<256, 256, 0, stream>>>(ctxpk, wom, bo, out);
}